// Round 11
// baseline (2001.904 us; speedup 1.0000x reference)
//
#include <hip/hip_runtime.h>
#include <cstdint>
#include <cstddef>

typedef unsigned long long u64;

__device__ inline u64 rfl64(u64 v){
  unsigned lo = __builtin_amdgcn_readfirstlane((unsigned)v);
  unsigned hi = __builtin_amdgcn_readfirstlane((unsigned)(v >> 32));
  return ((u64)hi << 32) | lo;
}

// ---------------- prep 1: weight tables + folded output weights ----------------
__global__ void prep_weights(const float* __restrict__ W1, const float* __restrict__ W2,
                             const float* __restrict__ W3, const float* __restrict__ Wc2,
                             const float* __restrict__ bc2, const float* __restrict__ WA,
                             float* __restrict__ Wt1g, float* __restrict__ Wt2f,
                             float* __restrict__ Wt3f, double* __restrict__ wEff,
                             double* __restrict__ bEff)
{
  int id = blockIdx.x * 256 + (int)threadIdx.x;
  if (id < 65536){ int i = id >> 8, j = id & 255; Wt2f[(i<<8)+j] = W2[j*256+i]; }  // Wt2f[i][j] = W2[j][i]
  else if (id < 65792){ Wt2f[id] = 0.0f; }                                          // zero row (idx 256)
  if (id < 3072){ int k = id >> 8, j = id & 255; Wt1g[(k<<8)+j] = W1[j*12+k]; }     // Wt1g[k][j]
  if (id < 1028){ int r = id >> 2, c = id & 3; Wt3f[id] = (r < 256 && c < 3) ? W3[c*256+r] : 0.0f; } // + zero row 256
  if (id < 32){ double s = 0.0; for (int c=0;c<64;c++) s += (double)WA[c]*(double)Wc2[c*32+id]; wEff[id] = s; }
  if (id == 32){ double s = 0.0; for (int c=0;c<64;c++) s += (double)WA[c]*(double)bc2[c]; *bEff = s; }
}

// ---------------- prep 2: rate-encode probabilities (f64) ----------------
__global__ void prep_probs(const float* __restrict__ x, double* __restrict__ probs, int B)
{
  int b = blockIdx.x, k = (int)threadIdx.x;
  if (b >= B || k >= 24) return;
  double* pb = probs + (size_t)b*24;
  if (k >= 18){ pb[k] = -1.0; return; }
  int fk, g0, gn;
  if (k < 12){ fk = k;          g0 = 0;  gn = 12; }
  else if (k < 15){ fk = 6+(k-12);  g0 = 6;  gn = 6; }
  else           { fk = 12+(k-15); g0 = 12; gn = 6; }
  const float* xb = x + (size_t)b*18;
  double mn = (double)xb[g0], mx = mn;
  for (int f = 1; f < gn; f++){ double v = (double)xb[g0+f]; mn = fmin(mn, v); mx = fmax(mx, v); }
  double rng = mx - mn; if (rng == 0.0) rng = 1.0;
  double norm = ((double)xb[fk] - mn) / rng;
  double p = (100.0 * norm) * 0.001;
  p = fmin(fmax(p, 0.0), 1.0);
  pb[k] = p;
}

// ---------------- prep 3: pack spike bits, TRANSPOSED to (b, t), t-padded with 2 zeros ----------------
__global__ void prep_enc(const float* __restrict__ u1, const float* __restrict__ u2,
                         const float* __restrict__ u3, const double* __restrict__ probs,
                         unsigned* __restrict__ encT, int B, int T)
{
  int b = blockIdx.x * blockDim.x + (int)threadIdx.x;
  int t = blockIdx.y;
  if (b >= B) return;
  if (t >= T){ encT[(size_t)b*(T+2) + t] = 0u; return; }
  const double* pb = probs + (size_t)b*24;
  size_t r = (size_t)t * B + b;
  const float* a1 = u1 + r*12;
  const float* a2 = u2 + r*6;
  const float* a3 = u3 + r*6;
  unsigned e = 0;
  #pragma unroll
  for (int k = 0; k < 12; k++) if ((double)a1[k] < pb[k])    e |= (1u << k);
  #pragma unroll
  for (int h = 0; h < 3; h++)  if ((double)a2[h] < pb[12+h]) e |= (1u << (12+h));
  #pragma unroll
  for (int h = 0; h < 3; h++)  if ((double)a3[h] < pb[15+h]) e |= (1u << (15+h));
  encT[(size_t)b*(T+2) + t] = e;
}

// ---------------- main: ONE ROW PER 128-THREAD BLOCK (2 cooperating waves) ----------------
// R10 pair-split: wave wv owns neurons [wv*128, wv*128+128) of layers 1-2 (2 per lane).
// Spike masks exchanged through 48B LDS with 2 barriers/step (write->bar->read; each
// buffer's rewrite is fenced from its last read by the other barrier). Wave 0 also runs
// L3/L4 and the output. 8192 blocks @ 16 blocks/CU residency -> 2 dispatch rounds
// (backfill smooths the heavy-row tail); per-row serial work per wave halves.
__global__ __launch_bounds__(128, 8) void snn_main(
    const unsigned* __restrict__ encT,
    const float* __restrict__ b1, const float* __restrict__ b2, const float* __restrict__ b3,
    const float* __restrict__ Wc1, const float* __restrict__ bc1,
    const float* __restrict__ Wt1g, const float* __restrict__ Wt2f, const float* __restrict__ Wt3f,
    const double* __restrict__ wEff, const double* __restrict__ bEff,
    float* __restrict__ out, int B, int T)
{
  __shared__ u64 xb1[2][2];   // [wave][mask] layer-1 spike masks
  __shared__ u64 xb2[2];      // wave-1's layer-2 masks (wave-0 consumes)

  const int tid  = (int)threadIdx.x;
  const int lane = tid & 63;
  const int wv   = tid >> 6;            // 0 or 1
  const int b    = blockIdx.x;
  if (b >= B) return;
  const int j2   = (wv << 7) + (lane << 1);   // this lane's first neuron (j2, j2+1)
  const int lcl  = (lane < 3) ? lane : 3;

  const float2 b1f = *(const float2*)(b1 + j2);
  const float2 b2f = *(const float2*)(b2 + j2);
  const double b3d = (lane < 3) ? (double)b3[lane] : 0.0;
  double wc1b=0.0, wEd=0.0, pre0=0.0, pre1=0.0, pre2=0.0, pre3=0.0;
  if (wv == 0 && lane < 32){
    double wa = (double)Wc1[lane*3+0];
    wc1b      = (double)Wc1[lane*3+1];
    double wc = (double)Wc1[lane*3+2];
    double bd = (double)bc1[lane];
    wEd  = wEff[lane];
    pre0 = bd;            // td=0, td2=0
    pre1 = bd + wa;       // td=1, td2=0
    pre2 = bd + wc;       // td=0, td2=1
    pre3 = bd + wa + wc;  // td=1, td2=1
  }

  double m10=0,m11=0;          // this wave's 2 layer-1 membranes per lane
  double m20=0,m21=0;          // layer-2
  double m3v=0;                // wave 0 only
  double m40=0,m41=0,m42=0;    // wave 0 only
  bool sp20=false,sp21=false;
  bool sp3v=false;
  bool sp40=false,sp41=false,sp42=false;

  const unsigned* encTb = encT + (size_t)b * (T + 2);
  unsigned e_cur = __builtin_amdgcn_readfirstlane(encTb[0]);
  unsigned e_nx  = __builtin_amdgcn_readfirstlane(encTb[1]);

  // prologue: layer-1 current for t=0 (no prior resets)
  double ca0 = (double)b1f.x, ca1 = (double)b1f.y;
  {
    unsigned w = e_cur & 0xFFFu;
    while (w){
      int k = __builtin_ctz(w); w &= w-1;
      const float2 r = *(const float2*)(Wt1g + (k<<8) + j2);
      ca0 += (double)r.x; ca1 += (double)r.y;
    }
  }

  for (int t = 0; t < T; t++){
    // ---- layer 1 membrane update ----
    m10 = fma(0.9, m10, ca0);
    m11 = fma(0.9, m11, ca1);
    const bool sp10 = m10 > 1.0;
    const bool sp11 = m11 > 1.0;
    const u64 bb0 = __ballot(sp10);     // bit l <-> neuron wv*128 + 2l
    const u64 bb1 = __ballot(sp11);     // bit l <-> neuron wv*128 + 2l + 1

    // publish this wave's L1 masks, fetch the other wave's
    if (lane < 2) xb1[wv][lane] = lane ? bb1 : bb0;
    __syncthreads();                                        // ---- bar 1 ----
    const u64 o0m = rfl64(xb1[wv^1][0]);
    const u64 o1m = rfl64(xb1[wv^1][1]);
    u64 q0, q1, q2, q3;        // masks in global neuron order
    if (wv == 0){ q0 = bb0; q1 = bb1; q2 = o0m; q3 = o1m; }
    else        { q0 = o0m; q1 = o1m; q2 = bb0; q3 = bb1; }
    // row(m, bit): i = (m>>1)*128 + (bit<<1) + (m&1);  PAD row = 256 (zeros)

    // ---- layer 2, window 1: extract + issue loads ----
    int i0 = q0 ? (int)(__builtin_ctzll(q0)<<1)           : 256;  q0 &= q0-1;
    int i1 = q1 ? (int)((__builtin_ctzll(q1)<<1)|1)       : 256;  q1 &= q1-1;
    int i2 = q2 ? (int)((__builtin_ctzll(q2)<<1)+128)     : 256;  q2 &= q2-1;
    int i3 = q3 ? (int)(((__builtin_ctzll(q3)<<1)|1)+128) : 256;  q3 &= q3-1;
    const float2 g0 = *(const float2*)(Wt2f + ((size_t)i0<<8) + j2);
    const float2 g1 = *(const float2*)(Wt2f + ((size_t)i1<<8) + j2);
    const float2 g2 = *(const float2*)(Wt2f + ((size_t)i2<<8) + j2);
    const float2 g3 = *(const float2*)(Wt2f + ((size_t)i3<<8) + j2);

    const unsigned e_n2 = encTb[t+2];   // enc prefetch (L1-hot)

    // ---- overlap window-1 latency: next-step layer-1 gather (L1-cache-hot) ----
    ca0 = (sp10 ? -1.0 : 0.0) + (double)b1f.x;
    ca1 = (sp11 ? -1.0 : 0.0) + (double)b1f.y;
    {
      unsigned w = e_nx & 0xFFFu;
      while (w){
        int k = __builtin_ctz(w); w &= w-1;
        const float2 r = *(const float2*)(Wt1g + (k<<8) + j2);
        ca0 += (double)r.x; ca1 += (double)r.y;
      }
    }

    // ---- consume window 1 (guarded) ----
    double c0 = (sp20 ? -1.0 : 0.0) + (double)b2f.x;
    double c1 = (sp21 ? -1.0 : 0.0) + (double)b2f.y;
    if (i0 != 256){ c0 += (double)g0.x; c1 += (double)g0.y; }
    if (i1 != 256){ c0 += (double)g1.x; c1 += (double)g1.y; }
    if (i2 != 256){ c0 += (double)g2.x; c1 += (double)g2.y; }
    if (i3 != 256){ c0 += (double)g3.x; c1 += (double)g3.y; }

    // ---- remaining windows ----
    while (q0 | q1 | q2 | q3){
      int j0 = q0 ? (int)(__builtin_ctzll(q0)<<1)           : 256;  q0 &= q0-1;
      int j1 = q1 ? (int)((__builtin_ctzll(q1)<<1)|1)       : 256;  q1 &= q1-1;
      int j2i= q2 ? (int)((__builtin_ctzll(q2)<<1)+128)     : 256;  q2 &= q2-1;
      int j3 = q3 ? (int)(((__builtin_ctzll(q3)<<1)|1)+128) : 256;  q3 &= q3-1;
      const float2 h0 = *(const float2*)(Wt2f + ((size_t)j0 <<8) + j2);
      const float2 h1 = *(const float2*)(Wt2f + ((size_t)j1 <<8) + j2);
      const float2 h2 = *(const float2*)(Wt2f + ((size_t)j2i<<8) + j2);
      const float2 h3 = *(const float2*)(Wt2f + ((size_t)j3 <<8) + j2);
      if (j0 != 256){ c0 += (double)h0.x; c1 += (double)h0.y; }
      if (j1 != 256){ c0 += (double)h1.x; c1 += (double)h1.y; }
      if (j2i!= 256){ c0 += (double)h2.x; c1 += (double)h2.y; }
      if (j3 != 256){ c0 += (double)h3.x; c1 += (double)h3.y; }
    }

    m20 = fma(0.9, m20, c0);
    m21 = fma(0.9, m21, c1);
    sp20 = m20 > 1.0;
    sp21 = m21 > 1.0;
    const u64 vb0 = __ballot(sp20);
    const u64 vb1 = __ballot(sp21);

    // publish wave-1's L2 masks (wave 0 consumes for L3)
    if (wv == 1 && lane < 2) xb2[lane] = lane ? vb1 : vb0;
    __syncthreads();                                        // ---- bar 2 ----

    if (wv == 0){
      u64 v0 = vb0, v1 = vb1;
      u64 v2 = rfl64(xb2[0]);
      u64 v3 = rfl64(xb2[1]);
      // ---- layer 3 (global Wt3f, L1-hot, zero row 256) ----
      double cl3 = (sp3v ? -1.0 : 0.0) + b3d;
      while (v0 | v1 | v2 | v3){
        int j0 = v0 ? (int)(__builtin_ctzll(v0)<<1)           : 256;  v0 &= v0-1;
        int j1 = v1 ? (int)((__builtin_ctzll(v1)<<1)|1)       : 256;  v1 &= v1-1;
        int j2i= v2 ? (int)((__builtin_ctzll(v2)<<1)+128)     : 256;  v2 &= v2-1;
        int j3 = v3 ? (int)(((__builtin_ctzll(v3)<<1)|1)+128) : 256;  v3 &= v3-1;
        if (j0 != 256) cl3 += (double)Wt3f[(j0 <<2) + lcl];
        if (j1 != 256) cl3 += (double)Wt3f[(j1 <<2) + lcl];
        if (j2i!= 256) cl3 += (double)Wt3f[(j2i<<2) + lcl];
        if (j3 != 256) cl3 += (double)Wt3f[(j3 <<2) + lcl];
      }
      m3v = fma(0.9, m3v, cl3);
      sp3v = m3v > 1.0;
      const unsigned s3 = (unsigned)(__ballot((lane < 3) && sp3v) & 7ull);

      // ---- layer 4 (conv1 LIF): lane<32 = out-channel o, h = 0..2 ----
      const unsigned td  = (e_cur >> 12) & 7u;
      const unsigned td2 = (e_cur >> 15) & 7u;
      double cur, t1v, t2v;
      t1v = (td2 & 1u) ? pre2 : pre0;  t2v = (td2 & 1u) ? pre3 : pre1;
      cur = (td & 1u) ? t2v : t1v;
      if (s3 & 1u) cur += wc1b;
      cur += sp40 ? -1.0 : 0.0;
      m40 = fma(0.9, m40, cur); sp40 = m40 > 1.0;
      t1v = (td2 & 2u) ? pre2 : pre0;  t2v = (td2 & 2u) ? pre3 : pre1;
      cur = (td & 2u) ? t2v : t1v;
      if (s3 & 2u) cur += wc1b;
      cur += sp41 ? -1.0 : 0.0;
      m41 = fma(0.9, m41, cur); sp41 = m41 > 1.0;
      t1v = (td2 & 4u) ? pre2 : pre0;  t2v = (td2 & 4u) ? pre3 : pre1;
      cur = (td & 4u) ? t2v : t1v;
      if (s3 & 4u) cur += wc1b;
      cur += sp42 ? -1.0 : 0.0;
      m42 = fma(0.9, m42, cur); sp42 = m42 > 1.0;
    }

    // ---- rotate enc pipeline ----
    e_cur = e_nx;
    e_nx  = __builtin_amdgcn_readfirstlane(e_n2);
  }

  // ---- output (wave 0): out[b,m] = bEff + sum_o spk4_final[o,m] * wEff[o] ----
  if (wv == 0){
    double o0 = sp40 ? wEd : 0.0;   // wEd = 0 for lane >= 32
    double o1 = sp41 ? wEd : 0.0;
    double o2 = sp42 ? wEd : 0.0;
    for (int off = 32; off > 0; off >>= 1){
      o0 += __shfl_xor(o0, off, 64);
      o1 += __shfl_xor(o1, off, 64);
      o2 += __shfl_xor(o2, off, 64);
    }
    if (lane == 0){
      const double be = *bEff;
      out[b*3+0] = (float)(o0 + be);
      out[b*3+1] = (float)(o1 + be);
      out[b*3+2] = (float)(o2 + be);
    }
  }
}

// ---------------- host ----------------
extern "C" void kernel_launch(void* const* d_in, const int* in_sizes, int n_in,
                              void* d_out, int out_size, void* d_ws, size_t ws_size,
                              hipStream_t stream)
{
  const float* x   = (const float*)d_in[0];
  const float* u1  = (const float*)d_in[1];
  const float* u2  = (const float*)d_in[2];
  const float* u3  = (const float*)d_in[3];
  const float* W1  = (const float*)d_in[4];
  const float* b1  = (const float*)d_in[5];
  const float* W2  = (const float*)d_in[6];
  const float* b2  = (const float*)d_in[7];
  const float* W3  = (const float*)d_in[8];
  const float* b3  = (const float*)d_in[9];
  const float* Wc1 = (const float*)d_in[10];
  const float* bc1 = (const float*)d_in[11];
  const float* Wc2 = (const float*)d_in[12];
  const float* bc2 = (const float*)d_in[13];
  const float* WA  = (const float*)d_in[14];
  float* out = (float*)d_out;

  const int B = in_sizes[0] / 18;
  const int T = in_sizes[1] / (B * 12);

  char* ws = (char*)d_ws;
  float*  Wt2f  = (float*)(ws + 0);                        // 257*256*4 = 263168
  float*  Wt1g  = (float*)(ws + 263168);                   // 12*256*4  = 12288
  float*  Wt3f  = (float*)(ws + 275456);                   // 257*4*4   = 4112 (pad to 4112->4120 align ok)
  double* wEff  = (double*)(ws + 279576);                  // 256   (279576 % 8 == 0)
  double* bEff  = (double*)(ws + 279832);                  // 8
  double* probs = (double*)(ws + 279840);                  // B*24*8
  unsigned* encT= (unsigned*)(ws + 279840 + (size_t)B*24*8); // B*(T+2)*4

  hipLaunchKernelGGL(prep_weights, dim3(257), dim3(256), 0, stream,
                     W1, W2, W3, Wc2, bc2, WA, Wt1g, Wt2f, Wt3f, wEff, bEff);
  hipLaunchKernelGGL(prep_probs, dim3(B), dim3(64), 0, stream, x, probs, B);
  hipLaunchKernelGGL(prep_enc, dim3((B+255)/256, T+2), dim3(256), 0, stream,
                     u1, u2, u3, probs, encT, B, T);
  hipLaunchKernelGGL(snn_main, dim3(B), dim3(128), 0, stream,
                     encT, b1, b2, b3, Wc1, bc1, Wt1g, Wt2f, Wt3f, wEff, bEff, out, B, T);
}

// Round 12
// 1451.894 us; speedup vs baseline: 1.3788x; 1.3788x over previous
//
#include <hip/hip_runtime.h>
#include <cstdint>
#include <cstddef>

typedef unsigned long long u64;

__device__ inline u64 rfl64(u64 v){
  unsigned lo = __builtin_amdgcn_readfirstlane((unsigned)v);
  unsigned hi = __builtin_amdgcn_readfirstlane((unsigned)(v >> 32));
  return ((u64)hi << 32) | lo;
}

// ---------------- prep 1: weight tables + folded output weights ----------------
__global__ void prep_weights(const float* __restrict__ W1, const float* __restrict__ W2,
                             const float* __restrict__ W3, const float* __restrict__ Wc2,
                             const float* __restrict__ bc2, const float* __restrict__ WA,
                             float* __restrict__ Wt1g, float* __restrict__ Wt2f,
                             float* __restrict__ Wt3f, double* __restrict__ wEff,
                             double* __restrict__ bEff)
{
  int id = blockIdx.x * 256 + (int)threadIdx.x;
  if (id < 65536){ int i = id >> 8, j = id & 255; Wt2f[(i<<8)+j] = W2[j*256+i]; }  // Wt2f[i][j] = W2[j][i]
  else if (id < 65792){ Wt2f[id] = 0.0f; }                                          // zero row (idx 256)
  if (id < 3072){ int k = id >> 8, j = id & 255; Wt1g[(k<<8)+j] = W1[j*12+k]; }     // Wt1g[k][j]
  if (id < 1028){ int r = id >> 2, c = id & 3; Wt3f[id] = (r < 256 && c < 3) ? W3[c*256+r] : 0.0f; } // + zero row 256
  if (id < 32){ double s = 0.0; for (int c=0;c<64;c++) s += (double)WA[c]*(double)Wc2[c*32+id]; wEff[id] = s; }
  if (id == 32){ double s = 0.0; for (int c=0;c<64;c++) s += (double)WA[c]*(double)bc2[c]; *bEff = s; }
}

// ---------------- prep 2: rate-encode probabilities (f64) ----------------
__global__ void prep_probs(const float* __restrict__ x, double* __restrict__ probs, int B)
{
  int b = blockIdx.x, k = (int)threadIdx.x;
  if (b >= B || k >= 24) return;
  double* pb = probs + (size_t)b*24;
  if (k >= 18){ pb[k] = -1.0; return; }
  int fk, g0, gn;
  if (k < 12){ fk = k;          g0 = 0;  gn = 12; }
  else if (k < 15){ fk = 6+(k-12);  g0 = 6;  gn = 6; }
  else           { fk = 12+(k-15); g0 = 12; gn = 6; }
  const float* xb = x + (size_t)b*18;
  double mn = (double)xb[g0], mx = mn;
  for (int f = 1; f < gn; f++){ double v = (double)xb[g0+f]; mn = fmin(mn, v); mx = fmax(mx, v); }
  double rng = mx - mn; if (rng == 0.0) rng = 1.0;
  double norm = ((double)xb[fk] - mn) / rng;
  double p = (100.0 * norm) * 0.001;
  p = fmin(fmax(p, 0.0), 1.0);
  pb[k] = p;
}

// ---------------- prep 3: pack spike bits, TRANSPOSED to (b, t), t-padded with 2 zeros ----------------
__global__ void prep_enc(const float* __restrict__ u1, const float* __restrict__ u2,
                         const float* __restrict__ u3, const double* __restrict__ probs,
                         unsigned* __restrict__ encT, int B, int T)
{
  int b = blockIdx.x * blockDim.x + (int)threadIdx.x;
  int t = blockIdx.y;
  if (b >= B) return;
  if (t >= T){ encT[(size_t)b*(T+2) + t] = 0u; return; }
  const double* pb = probs + (size_t)b*24;
  size_t r = (size_t)t * B + b;
  const float* a1 = u1 + r*12;
  const float* a2 = u2 + r*6;
  const float* a3 = u3 + r*6;
  unsigned e = 0;
  #pragma unroll
  for (int k = 0; k < 12; k++) if ((double)a1[k] < pb[k])    e |= (1u << k);
  #pragma unroll
  for (int h = 0; h < 3; h++)  if ((double)a2[h] < pb[12+h]) e |= (1u << (12+h));
  #pragma unroll
  for (int h = 0; h < 3; h++)  if ((double)a3[h] < pb[15+h]) e |= (1u << (15+h));
  encT[(size_t)b*(T+2) + t] = e;
}

// ---------------- main: ONE ROW PER 128-THREAD BLOCK (2 cooperating waves) ----------------
// R11 = R10 with the register cap REMOVED (__launch_bounds__(128), no min-waves arg).
// R10's 2 ms regression was scratch spill (WRITE_SIZE 1.17 GB, VGPR forced to 32);
// unconstrained the allocator should land ~56-64 VGPR -> natural 8 waves/EU, no spill.
__global__ __launch_bounds__(128) void snn_main(
    const unsigned* __restrict__ encT,
    const float* __restrict__ b1, const float* __restrict__ b2, const float* __restrict__ b3,
    const float* __restrict__ Wc1, const float* __restrict__ bc1,
    const float* __restrict__ Wt1g, const float* __restrict__ Wt2f, const float* __restrict__ Wt3f,
    const double* __restrict__ wEff, const double* __restrict__ bEff,
    float* __restrict__ out, int B, int T)
{
  __shared__ u64 xb1[2][2];   // [wave][mask] layer-1 spike masks
  __shared__ u64 xb2[2];      // wave-1's layer-2 masks (wave-0 consumes)

  const int tid  = (int)threadIdx.x;
  const int lane = tid & 63;
  const int wv   = tid >> 6;            // 0 or 1
  const int b    = blockIdx.x;
  if (b >= B) return;
  const int j2   = (wv << 7) + (lane << 1);   // this lane's first neuron (j2, j2+1)
  const int lcl  = (lane < 3) ? lane : 3;

  const float2 b1f = *(const float2*)(b1 + j2);
  const float2 b2f = *(const float2*)(b2 + j2);
  const double b3d = (lane < 3) ? (double)b3[lane] : 0.0;
  double wc1b=0.0, wEd=0.0, pre0=0.0, pre1=0.0, pre2=0.0, pre3=0.0;
  if (wv == 0 && lane < 32){
    double wa = (double)Wc1[lane*3+0];
    wc1b      = (double)Wc1[lane*3+1];
    double wc = (double)Wc1[lane*3+2];
    double bd = (double)bc1[lane];
    wEd  = wEff[lane];
    pre0 = bd;            // td=0, td2=0
    pre1 = bd + wa;       // td=1, td2=0
    pre2 = bd + wc;       // td=0, td2=1
    pre3 = bd + wa + wc;  // td=1, td2=1
  }

  double m10=0,m11=0;          // this wave's 2 layer-1 membranes per lane
  double m20=0,m21=0;          // layer-2
  double m3v=0;                // wave 0 only
  double m40=0,m41=0,m42=0;    // wave 0 only
  bool sp20=false,sp21=false;
  bool sp3v=false;
  bool sp40=false,sp41=false,sp42=false;

  const unsigned* encTb = encT + (size_t)b * (T + 2);
  unsigned e_cur = __builtin_amdgcn_readfirstlane(encTb[0]);
  unsigned e_nx  = __builtin_amdgcn_readfirstlane(encTb[1]);

  // prologue: layer-1 current for t=0 (no prior resets)
  double ca0 = (double)b1f.x, ca1 = (double)b1f.y;
  {
    unsigned w = e_cur & 0xFFFu;
    while (w){
      int k = __builtin_ctz(w); w &= w-1;
      const float2 r = *(const float2*)(Wt1g + (k<<8) + j2);
      ca0 += (double)r.x; ca1 += (double)r.y;
    }
  }

  for (int t = 0; t < T; t++){
    // ---- layer 1 membrane update ----
    m10 = fma(0.9, m10, ca0);
    m11 = fma(0.9, m11, ca1);
    const bool sp10 = m10 > 1.0;
    const bool sp11 = m11 > 1.0;
    const u64 bb0 = __ballot(sp10);     // bit l <-> neuron wv*128 + 2l
    const u64 bb1 = __ballot(sp11);     // bit l <-> neuron wv*128 + 2l + 1

    // publish this wave's L1 masks, fetch the other wave's
    if (lane < 2) xb1[wv][lane] = lane ? bb1 : bb0;
    __syncthreads();                                        // ---- bar 1 ----
    const u64 o0m = rfl64(xb1[wv^1][0]);
    const u64 o1m = rfl64(xb1[wv^1][1]);
    u64 q0, q1, q2, q3;        // masks in global neuron order
    if (wv == 0){ q0 = bb0; q1 = bb1; q2 = o0m; q3 = o1m; }
    else        { q0 = o0m; q1 = o1m; q2 = bb0; q3 = bb1; }
    // row(m, bit): i = (m>>1)*128 + (bit<<1) + (m&1);  PAD row = 256 (zeros)

    // ---- layer 2, window 1: extract + issue loads ----
    int i0 = q0 ? (int)(__builtin_ctzll(q0)<<1)           : 256;  q0 &= q0-1;
    int i1 = q1 ? (int)((__builtin_ctzll(q1)<<1)|1)       : 256;  q1 &= q1-1;
    int i2 = q2 ? (int)((__builtin_ctzll(q2)<<1)+128)     : 256;  q2 &= q2-1;
    int i3 = q3 ? (int)(((__builtin_ctzll(q3)<<1)|1)+128) : 256;  q3 &= q3-1;
    const float2 g0 = *(const float2*)(Wt2f + ((size_t)i0<<8) + j2);
    const float2 g1 = *(const float2*)(Wt2f + ((size_t)i1<<8) + j2);
    const float2 g2 = *(const float2*)(Wt2f + ((size_t)i2<<8) + j2);
    const float2 g3 = *(const float2*)(Wt2f + ((size_t)i3<<8) + j2);

    const unsigned e_n2 = encTb[t+2];   // enc prefetch (L1-hot)

    // ---- overlap window-1 latency: next-step layer-1 gather (L1-cache-hot) ----
    ca0 = (sp10 ? -1.0 : 0.0) + (double)b1f.x;
    ca1 = (sp11 ? -1.0 : 0.0) + (double)b1f.y;
    {
      unsigned w = e_nx & 0xFFFu;
      while (w){
        int k = __builtin_ctz(w); w &= w-1;
        const float2 r = *(const float2*)(Wt1g + (k<<8) + j2);
        ca0 += (double)r.x; ca1 += (double)r.y;
      }
    }

    // ---- consume window 1 (guarded) ----
    double c0 = (sp20 ? -1.0 : 0.0) + (double)b2f.x;
    double c1 = (sp21 ? -1.0 : 0.0) + (double)b2f.y;
    if (i0 != 256){ c0 += (double)g0.x; c1 += (double)g0.y; }
    if (i1 != 256){ c0 += (double)g1.x; c1 += (double)g1.y; }
    if (i2 != 256){ c0 += (double)g2.x; c1 += (double)g2.y; }
    if (i3 != 256){ c0 += (double)g3.x; c1 += (double)g3.y; }

    // ---- remaining windows ----
    while (q0 | q1 | q2 | q3){
      int j0 = q0 ? (int)(__builtin_ctzll(q0)<<1)           : 256;  q0 &= q0-1;
      int j1 = q1 ? (int)((__builtin_ctzll(q1)<<1)|1)       : 256;  q1 &= q1-1;
      int j2i= q2 ? (int)((__builtin_ctzll(q2)<<1)+128)     : 256;  q2 &= q2-1;
      int j3 = q3 ? (int)(((__builtin_ctzll(q3)<<1)|1)+128) : 256;  q3 &= q3-1;
      const float2 h0 = *(const float2*)(Wt2f + ((size_t)j0 <<8) + j2);
      const float2 h1 = *(const float2*)(Wt2f + ((size_t)j1 <<8) + j2);
      const float2 h2 = *(const float2*)(Wt2f + ((size_t)j2i<<8) + j2);
      const float2 h3 = *(const float2*)(Wt2f + ((size_t)j3 <<8) + j2);
      if (j0 != 256){ c0 += (double)h0.x; c1 += (double)h0.y; }
      if (j1 != 256){ c0 += (double)h1.x; c1 += (double)h1.y; }
      if (j2i!= 256){ c0 += (double)h2.x; c1 += (double)h2.y; }
      if (j3 != 256){ c0 += (double)h3.x; c1 += (double)h3.y; }
    }

    m20 = fma(0.9, m20, c0);
    m21 = fma(0.9, m21, c1);
    sp20 = m20 > 1.0;
    sp21 = m21 > 1.0;
    const u64 vb0 = __ballot(sp20);
    const u64 vb1 = __ballot(sp21);

    // publish wave-1's L2 masks (wave 0 consumes for L3)
    if (wv == 1 && lane < 2) xb2[lane] = lane ? vb1 : vb0;
    __syncthreads();                                        // ---- bar 2 ----

    if (wv == 0){
      u64 v0 = vb0, v1 = vb1;
      u64 v2 = rfl64(xb2[0]);
      u64 v3 = rfl64(xb2[1]);
      // ---- layer 3 (global Wt3f, L1-hot, zero row 256) ----
      double cl3 = (sp3v ? -1.0 : 0.0) + b3d;
      while (v0 | v1 | v2 | v3){
        int j0 = v0 ? (int)(__builtin_ctzll(v0)<<1)           : 256;  v0 &= v0-1;
        int j1 = v1 ? (int)((__builtin_ctzll(v1)<<1)|1)       : 256;  v1 &= v1-1;
        int j2i= v2 ? (int)((__builtin_ctzll(v2)<<1)+128)     : 256;  v2 &= v2-1;
        int j3 = v3 ? (int)(((__builtin_ctzll(v3)<<1)|1)+128) : 256;  v3 &= v3-1;
        if (j0 != 256) cl3 += (double)Wt3f[(j0 <<2) + lcl];
        if (j1 != 256) cl3 += (double)Wt3f[(j1 <<2) + lcl];
        if (j2i!= 256) cl3 += (double)Wt3f[(j2i<<2) + lcl];
        if (j3 != 256) cl3 += (double)Wt3f[(j3 <<2) + lcl];
      }
      m3v = fma(0.9, m3v, cl3);
      sp3v = m3v > 1.0;
      const unsigned s3 = (unsigned)(__ballot((lane < 3) && sp3v) & 7ull);

      // ---- layer 4 (conv1 LIF): lane<32 = out-channel o, h = 0..2 ----
      const unsigned td  = (e_cur >> 12) & 7u;
      const unsigned td2 = (e_cur >> 15) & 7u;
      double cur, t1v, t2v;
      t1v = (td2 & 1u) ? pre2 : pre0;  t2v = (td2 & 1u) ? pre3 : pre1;
      cur = (td & 1u) ? t2v : t1v;
      if (s3 & 1u) cur += wc1b;
      cur += sp40 ? -1.0 : 0.0;
      m40 = fma(0.9, m40, cur); sp40 = m40 > 1.0;
      t1v = (td2 & 2u) ? pre2 : pre0;  t2v = (td2 & 2u) ? pre3 : pre1;
      cur = (td & 2u) ? t2v : t1v;
      if (s3 & 2u) cur += wc1b;
      cur += sp41 ? -1.0 : 0.0;
      m41 = fma(0.9, m41, cur); sp41 = m41 > 1.0;
      t1v = (td2 & 4u) ? pre2 : pre0;  t2v = (td2 & 4u) ? pre3 : pre1;
      cur = (td & 4u) ? t2v : t1v;
      if (s3 & 4u) cur += wc1b;
      cur += sp42 ? -1.0 : 0.0;
      m42 = fma(0.9, m42, cur); sp42 = m42 > 1.0;
    }

    // ---- rotate enc pipeline ----
    e_cur = e_nx;
    e_nx  = __builtin_amdgcn_readfirstlane(e_n2);
  }

  // ---- output (wave 0): out[b,m] = bEff + sum_o spk4_final[o,m] * wEff[o] ----
  if (wv == 0){
    double o0 = sp40 ? wEd : 0.0;   // wEd = 0 for lane >= 32
    double o1 = sp41 ? wEd : 0.0;
    double o2 = sp42 ? wEd : 0.0;
    for (int off = 32; off > 0; off >>= 1){
      o0 += __shfl_xor(o0, off, 64);
      o1 += __shfl_xor(o1, off, 64);
      o2 += __shfl_xor(o2, off, 64);
    }
    if (lane == 0){
      const double be = *bEff;
      out[b*3+0] = (float)(o0 + be);
      out[b*3+1] = (float)(o1 + be);
      out[b*3+2] = (float)(o2 + be);
    }
  }
}

// ---------------- host ----------------
extern "C" void kernel_launch(void* const* d_in, const int* in_sizes, int n_in,
                              void* d_out, int out_size, void* d_ws, size_t ws_size,
                              hipStream_t stream)
{
  const float* x   = (const float*)d_in[0];
  const float* u1  = (const float*)d_in[1];
  const float* u2  = (const float*)d_in[2];
  const float* u3  = (const float*)d_in[3];
  const float* W1  = (const float*)d_in[4];
  const float* b1  = (const float*)d_in[5];
  const float* W2  = (const float*)d_in[6];
  const float* b2  = (const float*)d_in[7];
  const float* W3  = (const float*)d_in[8];
  const float* b3  = (const float*)d_in[9];
  const float* Wc1 = (const float*)d_in[10];
  const float* bc1 = (const float*)d_in[11];
  const float* Wc2 = (const float*)d_in[12];
  const float* bc2 = (const float*)d_in[13];
  const float* WA  = (const float*)d_in[14];
  float* out = (float*)d_out;

  const int B = in_sizes[0] / 18;
  const int T = in_sizes[1] / (B * 12);

  char* ws = (char*)d_ws;
  float*  Wt2f  = (float*)(ws + 0);                        // 257*256*4 = 263168
  float*  Wt1g  = (float*)(ws + 263168);                   // 12*256*4  = 12288
  float*  Wt3f  = (float*)(ws + 275456);                   // 257*4*4   = 4112
  double* wEff  = (double*)(ws + 279576);                  // 256
  double* bEff  = (double*)(ws + 279832);                  // 8
  double* probs = (double*)(ws + 279840);                  // B*24*8
  unsigned* encT= (unsigned*)(ws + 279840 + (size_t)B*24*8); // B*(T+2)*4

  hipLaunchKernelGGL(prep_weights, dim3(257), dim3(256), 0, stream,
                     W1, W2, W3, Wc2, bc2, WA, Wt1g, Wt2f, Wt3f, wEff, bEff);
  hipLaunchKernelGGL(prep_probs, dim3(B), dim3(64), 0, stream, x, probs, B);
  hipLaunchKernelGGL(prep_enc, dim3((B+255)/256, T+2), dim3(256), 0, stream,
                     u1, u2, u3, probs, encT, B, T);
  hipLaunchKernelGGL(snn_main, dim3(B), dim3(128), 0, stream,
                     encT, b1, b2, b3, Wc1, bc1, Wt1g, Wt2f, Wt3f, wEff, bEff, out, B, T);
}

// Round 13
// 941.303 us; speedup vs baseline: 2.1267x; 1.5424x over previous
//
#include <hip/hip_runtime.h>
#include <cstdint>
#include <cstddef>

typedef unsigned long long u64;

// ---------------- prep 1: W2 transpose (f32, + zero row 256) + folded output weights ----------------
__global__ void prep_weights(const float* __restrict__ W2, const float* __restrict__ Wc2,
                             const float* __restrict__ bc2, const float* __restrict__ WA,
                             float* __restrict__ Wt2f, double* __restrict__ wEff,
                             double* __restrict__ bEff)
{
  int id = blockIdx.x * 256 + (int)threadIdx.x;
  if (id < 65536){ int i = id >> 8, j = id & 255; Wt2f[(i<<8)+j] = W2[j*256+i]; }  // Wt2f[i][j] = W2[j][i]
  else if (id < 65792){ Wt2f[id] = 0.0f; }                                          // zero row (idx 256)
  if (id < 32){ double s = 0.0; for (int c=0;c<64;c++) s += (double)WA[c]*(double)Wc2[c*32+id]; wEff[id] = s; }
  if (id == 32){ double s = 0.0; for (int c=0;c<64;c++) s += (double)WA[c]*(double)bc2[c]; *bEff = s; }
}

// ---------------- prep 2: rate-encode probabilities (f64) ----------------
__global__ void prep_probs(const float* __restrict__ x, double* __restrict__ probs, int B)
{
  int b = blockIdx.x, k = (int)threadIdx.x;
  if (b >= B || k >= 24) return;
  double* pb = probs + (size_t)b*24;
  if (k >= 18){ pb[k] = -1.0; return; }
  int fk, g0, gn;
  if (k < 12){ fk = k;          g0 = 0;  gn = 12; }
  else if (k < 15){ fk = 6+(k-12);  g0 = 6;  gn = 6; }
  else           { fk = 12+(k-15); g0 = 12; gn = 6; }
  const float* xb = x + (size_t)b*18;
  double mn = (double)xb[g0], mx = mn;
  for (int f = 1; f < gn; f++){ double v = (double)xb[g0+f]; mn = fmin(mn, v); mx = fmax(mx, v); }
  double rng = mx - mn; if (rng == 0.0) rng = 1.0;
  double norm = ((double)xb[fk] - mn) / rng;
  double p = (100.0 * norm) * 0.001;
  p = fmin(fmax(p, 0.0), 1.0);
  pb[k] = p;
}

// ---------------- prep 3: pack spike bits, TRANSPOSED to (b, t), t-padded with 2 zeros ----------------
__global__ void prep_enc(const float* __restrict__ u1, const float* __restrict__ u2,
                         const float* __restrict__ u3, const double* __restrict__ probs,
                         unsigned* __restrict__ encT, int B, int T)
{
  int b = blockIdx.x * blockDim.x + (int)threadIdx.x;
  int t = blockIdx.y;
  if (b >= B) return;
  if (t >= T){ encT[(size_t)b*(T+2) + t] = 0u; return; }
  const double* pb = probs + (size_t)b*24;
  size_t r = (size_t)t * B + b;
  const float* a1 = u1 + r*12;
  const float* a2 = u2 + r*6;
  const float* a3 = u3 + r*6;
  unsigned e = 0;
  #pragma unroll
  for (int k = 0; k < 12; k++) if ((double)a1[k] < pb[k])    e |= (1u << k);
  #pragma unroll
  for (int h = 0; h < 3; h++)  if ((double)a2[h] < pb[12+h]) e |= (1u << (12+h));
  #pragma unroll
  for (int h = 0; h < 3; h++)  if ((double)a3[h] < pb[15+h]) e |= (1u << (15+h));
  encT[(size_t)b*(T+2) + t] = e;
}

// ---------------- main: TWO ROWS PER WAVE, interleaved (R8 per-row math, unchanged) ----------------
// R12: each wave owns rows rA and rB = rA + B/2 and runs both streams in straight-line
// interleave: both rows' window-1 loads (8x float4) issue before any consume; the
// remaining-windows loop is fused so both streams' loads stay co-issued. No duplicated
// work (unlike R10/R11) — pure added ILP to fill latency stalls + tail averaging.
__global__ __launch_bounds__(256) void snn_main(
    const unsigned* __restrict__ encT,
    const float* __restrict__ b1, const float* __restrict__ b2, const float* __restrict__ b3,
    const float* __restrict__ W1, const float* __restrict__ W3,
    const float* __restrict__ Wc1, const float* __restrict__ bc1,
    const float* __restrict__ Wt2f,
    const double* __restrict__ wEff, const double* __restrict__ bEff,
    float* __restrict__ out, int B, int T)
{
  __shared__ __align__(16) float s_w1[12*256];   // s_w1[k][j] = W1[j][k]
  __shared__ __align__(16) float s_w3[257*4];    // s_w3[i][c] = W3[c][i] (c<3), col3 + row256 = 0

  const int tid  = (int)threadIdx.x;
  const int lane = tid & 63;
  const int wid  = tid >> 6;
  const int half = (B + 1) >> 1;
  const int rA = blockIdx.x * 4 + wid;
  const int l4 = lane << 2;
  const int lcl = (lane < 3) ? lane : 3;

  for (int i = tid; i < 3072; i += 256){ int k = i >> 8, j = i & 255; s_w1[i] = W1[j*12+k]; }
  for (int i = tid; i < 1028; i += 256){
    int r = i >> 2, c = i & 3;
    s_w3[i] = (r < 256 && c < 3) ? W3[c*256 + r] : 0.0f;
  }
  __syncthreads();
  if (rA >= half) return;
  const int rB = rA + half;
  const bool hasB = rB < B;

  const float4 b1f = *(const float4*)(b1 + l4);
  const float4 b2f = *(const float4*)(b2 + l4);
  const double b3d = (lane < 3) ? (double)b3[lane] : 0.0;
  double wc1b=0.0, wEd=0.0, pre0=0.0, pre1=0.0, pre2=0.0, pre3=0.0;
  if (lane < 32){
    double wa = (double)Wc1[lane*3+0];
    wc1b      = (double)Wc1[lane*3+1];
    double wc = (double)Wc1[lane*3+2];
    double bd = (double)bc1[lane];
    wEd  = wEff[lane];
    pre0 = bd; pre1 = bd + wa; pre2 = bd + wc; pre3 = bd + wa + wc;
  }

  // ---- per-row state (A and B) ----
  double m10A=0,m11A=0,m12A=0,m13A=0, m20A=0,m21A=0,m22A=0,m23A=0, m3A=0, m40A=0,m41A=0,m42A=0;
  double m10B=0,m11B=0,m12B=0,m13B=0, m20B=0,m21B=0,m22B=0,m23B=0, m3B=0, m40B=0,m41B=0,m42B=0;
  bool s20A=false,s21A=false,s22A=false,s23A=false, s3A=false, s40A=false,s41A=false,s42A=false;
  bool s20B=false,s21B=false,s22B=false,s23B=false, s3B=false, s40B=false,s41B=false,s42B=false;

  const unsigned* ebA = encT + (size_t)rA * (T + 2);
  const unsigned* ebB = encT + (size_t)(hasB ? rB : 0) * (T + 2);
  unsigned eAc = __builtin_amdgcn_readfirstlane(ebA[0]);
  unsigned eAn = __builtin_amdgcn_readfirstlane(ebA[1]);
  unsigned eBc = __builtin_amdgcn_readfirstlane(ebB[0]);
  unsigned eBn = __builtin_amdgcn_readfirstlane(ebB[1]);

#define L1G(EMASK, CA0, CA1, CA2, CA3) { unsigned w = (EMASK) & 0xFFFu; \
    while (w){ int k = __builtin_ctz(w); w &= w-1; \
      const float4 r = *(const float4*)&s_w1[(k<<8) + l4]; \
      CA0 += (double)r.x; CA1 += (double)r.y; CA2 += (double)r.z; CA3 += (double)r.w; } }

  double caA0=(double)b1f.x, caA1=(double)b1f.y, caA2=(double)b1f.z, caA3=(double)b1f.w;
  double caB0=caA0, caB1=caA1, caB2=caA2, caB3=caA3;
  L1G(eAc, caA0, caA1, caA2, caA3)
  L1G(eBc, caB0, caB1, caB2, caB3)

#define SLOT(Wm, CW, DST) { DST = (Wm) ? (((int)__builtin_ctzll(Wm)<<2)|(CW)) : 256; Wm &= (Wm)-1; }

  for (int t = 0; t < T; t++){
    // ---- layer 1 membrane updates (A, B) + ballots ----
    m10A = fma(0.9, m10A, caA0);  m11A = fma(0.9, m11A, caA1);
    m12A = fma(0.9, m12A, caA2);  m13A = fma(0.9, m13A, caA3);
    m10B = fma(0.9, m10B, caB0);  m11B = fma(0.9, m11B, caB1);
    m12B = fma(0.9, m12B, caB2);  m13B = fma(0.9, m13B, caB3);
    const bool p10A = m10A > 1.0; u64 wA0 = __ballot(p10A);
    const bool p11A = m11A > 1.0; u64 wA1 = __ballot(p11A);
    const bool p12A = m12A > 1.0; u64 wA2 = __ballot(p12A);
    const bool p13A = m13A > 1.0; u64 wA3 = __ballot(p13A);
    const bool p10B = m10B > 1.0; u64 wB0 = __ballot(p10B);
    const bool p11B = m11B > 1.0; u64 wB1 = __ballot(p11B);
    const bool p12B = m12B > 1.0; u64 wB2 = __ballot(p12B);
    const bool p13B = m13B > 1.0; u64 wB3 = __ballot(p13B);

    // ---- window 1 for BOTH rows: extract + issue 8 loads before any consume ----
    int iA0, iA1, iA2, iA3, iB0, iB1, iB2, iB3;
    SLOT(wA0, 0, iA0) SLOT(wA1, 1, iA1) SLOT(wA2, 2, iA2) SLOT(wA3, 3, iA3)
    SLOT(wB0, 0, iB0) SLOT(wB1, 1, iB1) SLOT(wB2, 2, iB2) SLOT(wB3, 3, iB3)
    const float4 gA0 = *(const float4*)(Wt2f + ((size_t)iA0<<8) + l4);
    const float4 gA1 = *(const float4*)(Wt2f + ((size_t)iA1<<8) + l4);
    const float4 gA2 = *(const float4*)(Wt2f + ((size_t)iA2<<8) + l4);
    const float4 gA3 = *(const float4*)(Wt2f + ((size_t)iA3<<8) + l4);
    const float4 gB0 = *(const float4*)(Wt2f + ((size_t)iB0<<8) + l4);
    const float4 gB1 = *(const float4*)(Wt2f + ((size_t)iB1<<8) + l4);
    const float4 gB2 = *(const float4*)(Wt2f + ((size_t)iB2<<8) + l4);
    const float4 gB3 = *(const float4*)(Wt2f + ((size_t)iB3<<8) + l4);

    const unsigned eA2 = ebA[t+2];
    const unsigned eB2 = ebB[t+2];

    // ---- overlap: next-step layer-1 LDS gathers for both rows ----
    caA0 = (p10A ? -1.0 : 0.0) + (double)b1f.x;
    caA1 = (p11A ? -1.0 : 0.0) + (double)b1f.y;
    caA2 = (p12A ? -1.0 : 0.0) + (double)b1f.z;
    caA3 = (p13A ? -1.0 : 0.0) + (double)b1f.w;
    L1G(eAn, caA0, caA1, caA2, caA3)
    caB0 = (p10B ? -1.0 : 0.0) + (double)b1f.x;
    caB1 = (p11B ? -1.0 : 0.0) + (double)b1f.y;
    caB2 = (p12B ? -1.0 : 0.0) + (double)b1f.z;
    caB3 = (p13B ? -1.0 : 0.0) + (double)b1f.w;
    L1G(eBn, caB0, caB1, caB2, caB3)

    // ---- consume window 1 (guarded, per row, order preserved) ----
    double cA0 = (s20A ? -1.0 : 0.0) + (double)b2f.x;
    double cA1 = (s21A ? -1.0 : 0.0) + (double)b2f.y;
    double cA2 = (s22A ? -1.0 : 0.0) + (double)b2f.z;
    double cA3 = (s23A ? -1.0 : 0.0) + (double)b2f.w;
    if (iA0 != 256){ cA0 += (double)gA0.x; cA1 += (double)gA0.y; cA2 += (double)gA0.z; cA3 += (double)gA0.w; }
    if (iA1 != 256){ cA0 += (double)gA1.x; cA1 += (double)gA1.y; cA2 += (double)gA1.z; cA3 += (double)gA1.w; }
    if (iA2 != 256){ cA0 += (double)gA2.x; cA1 += (double)gA2.y; cA2 += (double)gA2.z; cA3 += (double)gA2.w; }
    if (iA3 != 256){ cA0 += (double)gA3.x; cA1 += (double)gA3.y; cA2 += (double)gA3.z; cA3 += (double)gA3.w; }
    double cB0 = (s20B ? -1.0 : 0.0) + (double)b2f.x;
    double cB1 = (s21B ? -1.0 : 0.0) + (double)b2f.y;
    double cB2 = (s22B ? -1.0 : 0.0) + (double)b2f.z;
    double cB3 = (s23B ? -1.0 : 0.0) + (double)b2f.w;
    if (iB0 != 256){ cB0 += (double)gB0.x; cB1 += (double)gB0.y; cB2 += (double)gB0.z; cB3 += (double)gB0.w; }
    if (iB1 != 256){ cB0 += (double)gB1.x; cB1 += (double)gB1.y; cB2 += (double)gB1.z; cB3 += (double)gB1.w; }
    if (iB2 != 256){ cB0 += (double)gB2.x; cB1 += (double)gB2.y; cB2 += (double)gB2.z; cB3 += (double)gB2.w; }
    if (iB3 != 256){ cB0 += (double)gB3.x; cB1 += (double)gB3.y; cB2 += (double)gB3.z; cB3 += (double)gB3.w; }

    // ---- fused remaining windows: both rows' loads co-issued ----
    while (wA0 | wA1 | wA2 | wA3 | wB0 | wB1 | wB2 | wB3){
      int jA0, jA1, jA2, jA3, jB0, jB1, jB2, jB3;
      SLOT(wA0, 0, jA0) SLOT(wA1, 1, jA1) SLOT(wA2, 2, jA2) SLOT(wA3, 3, jA3)
      SLOT(wB0, 0, jB0) SLOT(wB1, 1, jB1) SLOT(wB2, 2, jB2) SLOT(wB3, 3, jB3)
      const float4 hA0 = *(const float4*)(Wt2f + ((size_t)jA0<<8) + l4);
      const float4 hA1 = *(const float4*)(Wt2f + ((size_t)jA1<<8) + l4);
      const float4 hA2 = *(const float4*)(Wt2f + ((size_t)jA2<<8) + l4);
      const float4 hA3 = *(const float4*)(Wt2f + ((size_t)jA3<<8) + l4);
      const float4 hB0 = *(const float4*)(Wt2f + ((size_t)jB0<<8) + l4);
      const float4 hB1 = *(const float4*)(Wt2f + ((size_t)jB1<<8) + l4);
      const float4 hB2 = *(const float4*)(Wt2f + ((size_t)jB2<<8) + l4);
      const float4 hB3 = *(const float4*)(Wt2f + ((size_t)jB3<<8) + l4);
      if (jA0 != 256){ cA0 += (double)hA0.x; cA1 += (double)hA0.y; cA2 += (double)hA0.z; cA3 += (double)hA0.w; }
      if (jA1 != 256){ cA0 += (double)hA1.x; cA1 += (double)hA1.y; cA2 += (double)hA1.z; cA3 += (double)hA1.w; }
      if (jA2 != 256){ cA0 += (double)hA2.x; cA1 += (double)hA2.y; cA2 += (double)hA2.z; cA3 += (double)hA2.w; }
      if (jA3 != 256){ cA0 += (double)hA3.x; cA1 += (double)hA3.y; cA2 += (double)hA3.z; cA3 += (double)hA3.w; }
      if (jB0 != 256){ cB0 += (double)hB0.x; cB1 += (double)hB0.y; cB2 += (double)hB0.z; cB3 += (double)hB0.w; }
      if (jB1 != 256){ cB0 += (double)hB1.x; cB1 += (double)hB1.y; cB2 += (double)hB1.z; cB3 += (double)hB1.w; }
      if (jB2 != 256){ cB0 += (double)hB2.x; cB1 += (double)hB2.y; cB2 += (double)hB2.z; cB3 += (double)hB2.w; }
      if (jB3 != 256){ cB0 += (double)hB3.x; cB1 += (double)hB3.y; cB2 += (double)hB3.z; cB3 += (double)hB3.w; }
    }

    // ---- layer 2 membrane updates + ballots ----
    m20A = fma(0.9, m20A, cA0);  m21A = fma(0.9, m21A, cA1);
    m22A = fma(0.9, m22A, cA2);  m23A = fma(0.9, m23A, cA3);
    m20B = fma(0.9, m20B, cB0);  m21B = fma(0.9, m21B, cB1);
    m22B = fma(0.9, m22B, cB2);  m23B = fma(0.9, m23B, cB3);
    s20A = m20A > 1.0; u64 vA0 = __ballot(s20A);
    s21A = m21A > 1.0; u64 vA1 = __ballot(s21A);
    s22A = m22A > 1.0; u64 vA2 = __ballot(s22A);
    s23A = m23A > 1.0; u64 vA3 = __ballot(s23A);
    s20B = m20B > 1.0; u64 vB0 = __ballot(s20B);
    s21B = m21B > 1.0; u64 vB1 = __ballot(s21B);
    s22B = m22B > 1.0; u64 vB2 = __ballot(s22B);
    s23B = m23B > 1.0; u64 vB3 = __ballot(s23B);

    // ---- layer 3 from LDS (per row, guarded slots) ----
    double cl3A = (s3A ? -1.0 : 0.0) + b3d;
    while (vA0 | vA1 | vA2 | vA3){
      int j0, j1, j2, j3;
      SLOT(vA0, 0, j0) SLOT(vA1, 1, j1) SLOT(vA2, 2, j2) SLOT(vA3, 3, j3)
      if (j0 != 256) cl3A += (double)s_w3[(j0<<2) + lcl];
      if (j1 != 256) cl3A += (double)s_w3[(j1<<2) + lcl];
      if (j2 != 256) cl3A += (double)s_w3[(j2<<2) + lcl];
      if (j3 != 256) cl3A += (double)s_w3[(j3<<2) + lcl];
    }
    m3A = fma(0.9, m3A, cl3A);
    s3A = m3A > 1.0;
    const unsigned q3A = (unsigned)(__ballot((lane < 3) && s3A) & 7ull);

    double cl3B = (s3B ? -1.0 : 0.0) + b3d;
    while (vB0 | vB1 | vB2 | vB3){
      int j0, j1, j2, j3;
      SLOT(vB0, 0, j0) SLOT(vB1, 1, j1) SLOT(vB2, 2, j2) SLOT(vB3, 3, j3)
      if (j0 != 256) cl3B += (double)s_w3[(j0<<2) + lcl];
      if (j1 != 256) cl3B += (double)s_w3[(j1<<2) + lcl];
      if (j2 != 256) cl3B += (double)s_w3[(j2<<2) + lcl];
      if (j3 != 256) cl3B += (double)s_w3[(j3<<2) + lcl];
    }
    m3B = fma(0.9, m3B, cl3B);
    s3B = m3B > 1.0;
    const unsigned q3B = (unsigned)(__ballot((lane < 3) && s3B) & 7ull);

    // ---- layer 4 (per row) ----
    {
      const unsigned td  = (eAc >> 12) & 7u;
      const unsigned td2 = (eAc >> 15) & 7u;
      double cur, t1, t2;
      t1 = (td2 & 1u) ? pre2 : pre0;  t2 = (td2 & 1u) ? pre3 : pre1;
      cur = (td & 1u) ? t2 : t1;  if (q3A & 1u) cur += wc1b;  cur += s40A ? -1.0 : 0.0;
      m40A = fma(0.9, m40A, cur); s40A = m40A > 1.0;
      t1 = (td2 & 2u) ? pre2 : pre0;  t2 = (td2 & 2u) ? pre3 : pre1;
      cur = (td & 2u) ? t2 : t1;  if (q3A & 2u) cur += wc1b;  cur += s41A ? -1.0 : 0.0;
      m41A = fma(0.9, m41A, cur); s41A = m41A > 1.0;
      t1 = (td2 & 4u) ? pre2 : pre0;  t2 = (td2 & 4u) ? pre3 : pre1;
      cur = (td & 4u) ? t2 : t1;  if (q3A & 4u) cur += wc1b;  cur += s42A ? -1.0 : 0.0;
      m42A = fma(0.9, m42A, cur); s42A = m42A > 1.0;
    }
    {
      const unsigned td  = (eBc >> 12) & 7u;
      const unsigned td2 = (eBc >> 15) & 7u;
      double cur, t1, t2;
      t1 = (td2 & 1u) ? pre2 : pre0;  t2 = (td2 & 1u) ? pre3 : pre1;
      cur = (td & 1u) ? t2 : t1;  if (q3B & 1u) cur += wc1b;  cur += s40B ? -1.0 : 0.0;
      m40B = fma(0.9, m40B, cur); s40B = m40B > 1.0;
      t1 = (td2 & 2u) ? pre2 : pre0;  t2 = (td2 & 2u) ? pre3 : pre1;
      cur = (td & 2u) ? t2 : t1;  if (q3B & 2u) cur += wc1b;  cur += s41B ? -1.0 : 0.0;
      m41B = fma(0.9, m41B, cur); s41B = m41B > 1.0;
      t1 = (td2 & 4u) ? pre2 : pre0;  t2 = (td2 & 4u) ? pre3 : pre1;
      cur = (td & 4u) ? t2 : t1;  if (q3B & 4u) cur += wc1b;  cur += s42B ? -1.0 : 0.0;
      m42B = fma(0.9, m42B, cur); s42B = m42B > 1.0;
    }

    // ---- rotate enc pipelines ----
    eAc = eAn;  eAn = __builtin_amdgcn_readfirstlane(eA2);
    eBc = eBn;  eBn = __builtin_amdgcn_readfirstlane(eB2);
  }

  // ---- outputs ----
  const double be = *bEff;
  {
    double o0 = s40A ? wEd : 0.0, o1 = s41A ? wEd : 0.0, o2 = s42A ? wEd : 0.0;
    for (int off = 32; off > 0; off >>= 1){
      o0 += __shfl_xor(o0, off, 64);
      o1 += __shfl_xor(o1, off, 64);
      o2 += __shfl_xor(o2, off, 64);
    }
    if (lane == 0){
      out[rA*3+0] = (float)(o0 + be);
      out[rA*3+1] = (float)(o1 + be);
      out[rA*3+2] = (float)(o2 + be);
    }
  }
  if (hasB){
    double o0 = s40B ? wEd : 0.0, o1 = s41B ? wEd : 0.0, o2 = s42B ? wEd : 0.0;
    for (int off = 32; off > 0; off >>= 1){
      o0 += __shfl_xor(o0, off, 64);
      o1 += __shfl_xor(o1, off, 64);
      o2 += __shfl_xor(o2, off, 64);
    }
    if (lane == 0){
      out[rB*3+0] = (float)(o0 + be);
      out[rB*3+1] = (float)(o1 + be);
      out[rB*3+2] = (float)(o2 + be);
    }
  }
}

// ---------------- host ----------------
extern "C" void kernel_launch(void* const* d_in, const int* in_sizes, int n_in,
                              void* d_out, int out_size, void* d_ws, size_t ws_size,
                              hipStream_t stream)
{
  const float* x   = (const float*)d_in[0];
  const float* u1  = (const float*)d_in[1];
  const float* u2  = (const float*)d_in[2];
  const float* u3  = (const float*)d_in[3];
  const float* W1  = (const float*)d_in[4];
  const float* b1  = (const float*)d_in[5];
  const float* W2  = (const float*)d_in[6];
  const float* b2  = (const float*)d_in[7];
  const float* W3  = (const float*)d_in[8];
  const float* b3  = (const float*)d_in[9];
  const float* Wc1 = (const float*)d_in[10];
  const float* bc1 = (const float*)d_in[11];
  const float* Wc2 = (const float*)d_in[12];
  const float* bc2 = (const float*)d_in[13];
  const float* WA  = (const float*)d_in[14];
  float* out = (float*)d_out;

  const int B = in_sizes[0] / 18;
  const int T = in_sizes[1] / (B * 12);

  char* ws = (char*)d_ws;
  float*  Wt2f  = (float*)(ws + 0);                        // 257*256*4 = 263168
  double* wEff  = (double*)(ws + 263168);                  // 256
  double* bEff  = (double*)(ws + 263424);                  // 8
  double* probs = (double*)(ws + 263432);                  // B*24*8
  unsigned* encT= (unsigned*)(ws + 263432 + (size_t)B*24*8); // B*(T+2)*4

  hipLaunchKernelGGL(prep_weights, dim3(257), dim3(256), 0, stream,
                     W2, Wc2, bc2, WA, Wt2f, wEff, bEff);
  hipLaunchKernelGGL(prep_probs, dim3(B), dim3(64), 0, stream, x, probs, B);
  hipLaunchKernelGGL(prep_enc, dim3((B+255)/256, T+2), dim3(256), 0, stream,
                     u1, u2, u3, probs, encT, B, T);
  const int half = (B + 1) >> 1;
  hipLaunchKernelGGL(snn_main, dim3((half+3)/4), dim3(256), 0, stream,
                     encT, b1, b2, b3, W1, W3, Wc1, bc1, Wt2f, wEff, bEff, out, B, T);
}

// Round 14
// 710.335 us; speedup vs baseline: 2.8183x; 1.3252x over previous
//
#include <hip/hip_runtime.h>
#include <cstdint>
#include <cstddef>

typedef unsigned long long u64;

// ---------------- prep 1: W2 transpose (f32, + zero row 256) + folded output weights ----------------
__global__ void prep_weights(const float* __restrict__ W2, const float* __restrict__ Wc2,
                             const float* __restrict__ bc2, const float* __restrict__ WA,
                             float* __restrict__ Wt2f, double* __restrict__ wEff,
                             double* __restrict__ bEff)
{
  int id = blockIdx.x * 256 + (int)threadIdx.x;
  if (id < 65536){ int i = id >> 8, j = id & 255; Wt2f[(i<<8)+j] = W2[j*256+i]; }  // Wt2f[i][j] = W2[j][i]
  else if (id < 65792){ Wt2f[id] = 0.0f; }                                          // zero row (idx 256)
  if (id < 32){ double s = 0.0; for (int c=0;c<64;c++) s += (double)WA[c]*(double)Wc2[c*32+id]; wEff[id] = s; }
  if (id == 32){ double s = 0.0; for (int c=0;c<64;c++) s += (double)WA[c]*(double)bc2[c]; *bEff = s; }
}

// ---------------- prep 1b: layer-1 mask tables  S[h][m][j] = sum_{k in m} W1[j][6h+k] (f64) ----------------
__global__ void prep_tab(const float* __restrict__ W1, double* __restrict__ Stab)
{
  int id = blockIdx.x * 256 + (int)threadIdx.x;      // 2*64*256 = 32768
  if (id >= 32768) return;
  int h = id >> 14, m = (id >> 8) & 63, j = id & 255;
  double s = 0.0;
  #pragma unroll
  for (int k = 0; k < 6; k++)
    if ((m >> k) & 1) s += (double)W1[j*12 + 6*h + k];
  Stab[id] = s;                                       // layout: [(h<<6)+m][j]
}

// ---------------- prep 2: rate-encode probabilities (f64) ----------------
__global__ void prep_probs(const float* __restrict__ x, double* __restrict__ probs, int B)
{
  int b = blockIdx.x, k = (int)threadIdx.x;
  if (b >= B || k >= 24) return;
  double* pb = probs + (size_t)b*24;
  if (k >= 18){ pb[k] = -1.0; return; }
  int fk, g0, gn;
  if (k < 12){ fk = k;          g0 = 0;  gn = 12; }
  else if (k < 15){ fk = 6+(k-12);  g0 = 6;  gn = 6; }
  else           { fk = 12+(k-15); g0 = 12; gn = 6; }
  const float* xb = x + (size_t)b*18;
  double mn = (double)xb[g0], mx = mn;
  for (int f = 1; f < gn; f++){ double v = (double)xb[g0+f]; mn = fmin(mn, v); mx = fmax(mx, v); }
  double rng = mx - mn; if (rng == 0.0) rng = 1.0;
  double norm = ((double)xb[fk] - mn) / rng;
  double p = (100.0 * norm) * 0.001;
  p = fmin(fmax(p, 0.0), 1.0);
  pb[k] = p;
}

// ---------------- prep 3: pack spike bits, TRANSPOSED to (b, t), t-padded with 2 zeros ----------------
__global__ void prep_enc(const float* __restrict__ u1, const float* __restrict__ u2,
                         const float* __restrict__ u3, const double* __restrict__ probs,
                         unsigned* __restrict__ encT, int B, int T)
{
  int b = blockIdx.x * blockDim.x + (int)threadIdx.x;
  int t = blockIdx.y;
  if (b >= B) return;
  if (t >= T){ encT[(size_t)b*(T+2) + t] = 0u; return; }
  const double* pb = probs + (size_t)b*24;
  size_t r = (size_t)t * B + b;
  const float* a1 = u1 + r*12;
  const float* a2 = u2 + r*6;
  const float* a3 = u3 + r*6;
  unsigned e = 0;
  #pragma unroll
  for (int k = 0; k < 12; k++) if ((double)a1[k] < pb[k])    e |= (1u << k);
  #pragma unroll
  for (int h = 0; h < 3; h++)  if ((double)a2[h] < pb[12+h]) e |= (1u << (12+h));
  #pragma unroll
  for (int h = 0; h < 3; h++)  if ((double)a3[h] < pb[15+h]) e |= (1u << (15+h));
  encT[(size_t)b*(T+2) + t] = e;
}

// ---------------- main: one wave per batch row (R8 structure) ----------------
// R13 = R8 with the layer-1 gather loop replaced by precomputed 6+6-bit mask tables:
// cur1 = reset + b1 + Slo[e&63][j] + Shi[(e>>6)&63][j]. Table rows for step t+1 are
// prefetched during step t (addresses depend only on enc), so the load latency hides
// under the step's L2 gather; ~150 cy/step of LDS-gather VALU work is deleted.
__global__ __launch_bounds__(256) void snn_main(
    const unsigned* __restrict__ encT,
    const float* __restrict__ b1, const float* __restrict__ b2, const float* __restrict__ b3,
    const float* __restrict__ W3,
    const float* __restrict__ Wc1, const float* __restrict__ bc1,
    const float* __restrict__ Wt2f, const double* __restrict__ Stab,
    const double* __restrict__ wEff, const double* __restrict__ bEff,
    float* __restrict__ out, int B, int T)
{
  __shared__ __align__(16) float s_w3[257*4];    // s_w3[i][c] = W3[c][i] (c<3), col3 + row256 = 0

  const int tid  = (int)threadIdx.x;
  const int lane = tid & 63;
  const int wid  = tid >> 6;
  const int b = blockIdx.x * 4 + wid;
  const int l4 = lane << 2;
  const int lcl = (lane < 3) ? lane : 3;

  for (int i = tid; i < 1028; i += 256){
    int r = i >> 2, c = i & 3;
    s_w3[i] = (r < 256 && c < 3) ? W3[c*256 + r] : 0.0f;
  }
  __syncthreads();
  if (b >= B) return;

  const float4 b1f = *(const float4*)(b1 + l4);   // f32 biases; cvt at use (exact)
  const float4 b2f = *(const float4*)(b2 + l4);
  const double b3d = (lane < 3) ? (double)b3[lane] : 0.0;
  double wc1b=0.0, wEd=0.0, pre0=0.0, pre1=0.0, pre2=0.0, pre3=0.0;
  if (lane < 32){
    double wa = (double)Wc1[lane*3+0];
    wc1b      = (double)Wc1[lane*3+1];
    double wc = (double)Wc1[lane*3+2];
    double bd = (double)bc1[lane];
    wEd  = wEff[lane];
    pre0 = bd;            // td=0, td2=0
    pre1 = bd + wa;       // td=1, td2=0
    pre2 = bd + wc;       // td=0, td2=1
    pre3 = bd + wa + wc;  // td=1, td2=1
  }

  double m10=0,m11=0,m12=0,m13=0;
  double m20=0,m21=0,m22=0,m23=0;
  double m3v=0;
  double m40=0,m41=0,m42=0;
  bool sp10=false,sp11=false,sp12=false,sp13=false;
  bool sp20=false,sp21=false,sp22=false,sp23=false;
  bool sp3v=false;
  bool sp40=false,sp41=false,sp42=false;

  const unsigned* encTb = encT + (size_t)b * (T + 2);

  unsigned e_cur = __builtin_amdgcn_readfirstlane(encTb[0]);
  unsigned e_nx  = __builtin_amdgcn_readfirstlane(encTb[1]);

  // prologue: table rows for t=0
  const double* rowL0 = Stab + ((size_t)(e_cur & 63u) << 8);
  const double* rowH0 = Stab + ((size_t)(64u + ((e_cur >> 6) & 63u)) << 8);
  double2 loA = *(const double2*)(rowL0 + l4), loB = *(const double2*)(rowL0 + l4 + 2);
  double2 hiA = *(const double2*)(rowH0 + l4), hiB = *(const double2*)(rowH0 + l4 + 2);

  for (int t = 0; t < T; t++){
    // ---- layer 1: cur = reset + b1 + Slo + Shi (tables preloaded) ----
    m10 = fma(0.9, m10, (sp10 ? -1.0 : 0.0) + (double)b1f.x + loA.x + hiA.x);
    m11 = fma(0.9, m11, (sp11 ? -1.0 : 0.0) + (double)b1f.y + loA.y + hiA.y);
    m12 = fma(0.9, m12, (sp12 ? -1.0 : 0.0) + (double)b1f.z + loB.x + hiB.x);
    m13 = fma(0.9, m13, (sp13 ? -1.0 : 0.0) + (double)b1f.w + loB.y + hiB.y);
    sp10 = m10 > 1.0; u64 w0  = __ballot(sp10);
    sp11 = m11 > 1.0; u64 w1  = __ballot(sp11);
    sp12 = m12 > 1.0; u64 w2  = __ballot(sp12);
    sp13 = m13 > 1.0; u64 w3m = __ballot(sp13);

    // ---- layer 2, window 1: one row per CW-mask (zero-row 256 when empty) ----
    int i0 = w0  ? (((int)__builtin_ctzll(w0) <<2)|0) : 256;  w0  &= w0 -1;
    int i1 = w1  ? (((int)__builtin_ctzll(w1) <<2)|1) : 256;  w1  &= w1 -1;
    int i2 = w2  ? (((int)__builtin_ctzll(w2) <<2)|2) : 256;  w2  &= w2 -1;
    int i3 = w3m ? (((int)__builtin_ctzll(w3m)<<2)|3) : 256;  w3m &= w3m-1;
    const float4 g0 = *(const float4*)(Wt2f + ((size_t)i0<<8) + l4);
    const float4 g1 = *(const float4*)(Wt2f + ((size_t)i1<<8) + l4);
    const float4 g2 = *(const float4*)(Wt2f + ((size_t)i2<<8) + l4);
    const float4 g3 = *(const float4*)(Wt2f + ((size_t)i3<<8) + l4);

    // ---- prefetch next-step table rows (addresses depend only on enc) ----
    const double* rowLn = Stab + ((size_t)(e_nx & 63u) << 8);
    const double* rowHn = Stab + ((size_t)(64u + ((e_nx >> 6) & 63u)) << 8);
    const double2 loAn = *(const double2*)(rowLn + l4), loBn = *(const double2*)(rowLn + l4 + 2);
    const double2 hiAn = *(const double2*)(rowHn + l4), hiBn = *(const double2*)(rowHn + l4 + 2);

    // prefetch enc for t+2 (sequential 4B, L1-hot; padded rows give 0 past T-1)
    const unsigned e_n2 = encTb[t+2];

    // ---- consume window 1: skip padded slots (wave-uniform branches) ----
    double c0 = (sp20 ? -1.0 : 0.0) + (double)b2f.x;
    double c1 = (sp21 ? -1.0 : 0.0) + (double)b2f.y;
    double c2 = (sp22 ? -1.0 : 0.0) + (double)b2f.z;
    double c3 = (sp23 ? -1.0 : 0.0) + (double)b2f.w;
    if (i0 != 256){ c0 += (double)g0.x; c1 += (double)g0.y; c2 += (double)g0.z; c3 += (double)g0.w; }
    if (i1 != 256){ c0 += (double)g1.x; c1 += (double)g1.y; c2 += (double)g1.z; c3 += (double)g1.w; }
    if (i2 != 256){ c0 += (double)g2.x; c1 += (double)g2.y; c2 += (double)g2.z; c3 += (double)g2.w; }
    if (i3 != 256){ c0 += (double)g3.x; c1 += (double)g3.y; c2 += (double)g3.z; c3 += (double)g3.w; }

    // ---- remaining windows: loads unconditional, consumes guarded ----
    while (w0 | w1 | w2 | w3m){
      int j0 = w0  ? (((int)__builtin_ctzll(w0) <<2)|0) : 256;  w0  &= w0 -1;
      int j1 = w1  ? (((int)__builtin_ctzll(w1) <<2)|1) : 256;  w1  &= w1 -1;
      int j2 = w2  ? (((int)__builtin_ctzll(w2) <<2)|2) : 256;  w2  &= w2 -1;
      int j3 = w3m ? (((int)__builtin_ctzll(w3m)<<2)|3) : 256;  w3m &= w3m-1;
      const float4 h0 = *(const float4*)(Wt2f + ((size_t)j0<<8) + l4);
      const float4 h1 = *(const float4*)(Wt2f + ((size_t)j1<<8) + l4);
      const float4 h2 = *(const float4*)(Wt2f + ((size_t)j2<<8) + l4);
      const float4 h3 = *(const float4*)(Wt2f + ((size_t)j3<<8) + l4);
      if (j0 != 256){ c0 += (double)h0.x; c1 += (double)h0.y; c2 += (double)h0.z; c3 += (double)h0.w; }
      if (j1 != 256){ c0 += (double)h1.x; c1 += (double)h1.y; c2 += (double)h1.z; c3 += (double)h1.w; }
      if (j2 != 256){ c0 += (double)h2.x; c1 += (double)h2.y; c2 += (double)h2.z; c3 += (double)h2.w; }
      if (j3 != 256){ c0 += (double)h3.x; c1 += (double)h3.y; c2 += (double)h3.z; c3 += (double)h3.w; }
    }

    m20 = fma(0.9, m20, c0);
    m21 = fma(0.9, m21, c1);
    m22 = fma(0.9, m22, c2);
    m23 = fma(0.9, m23, c3);
    sp20 = m20 > 1.0; u64 v0 = __ballot(sp20);
    sp21 = m21 > 1.0; u64 v1 = __ballot(sp21);
    sp22 = m22 > 1.0; u64 v2 = __ballot(sp22);
    sp23 = m23 > 1.0; u64 v3 = __ballot(sp23);

    // ---- layer 3 from LDS: consumes guarded per slot ----
    double cl3 = (sp3v ? -1.0 : 0.0) + b3d;
    while (v0 | v1 | v2 | v3){
      int j0 = v0 ? (((int)__builtin_ctzll(v0)<<2)|0) : 256;  v0 &= v0-1;
      int j1 = v1 ? (((int)__builtin_ctzll(v1)<<2)|1) : 256;  v1 &= v1-1;
      int j2 = v2 ? (((int)__builtin_ctzll(v2)<<2)|2) : 256;  v2 &= v2-1;
      int j3 = v3 ? (((int)__builtin_ctzll(v3)<<2)|3) : 256;  v3 &= v3-1;
      if (j0 != 256) cl3 += (double)s_w3[(j0<<2) + lcl];
      if (j1 != 256) cl3 += (double)s_w3[(j1<<2) + lcl];
      if (j2 != 256) cl3 += (double)s_w3[(j2<<2) + lcl];
      if (j3 != 256) cl3 += (double)s_w3[(j3<<2) + lcl];
    }
    m3v = fma(0.9, m3v, cl3);
    sp3v = m3v > 1.0;
    const unsigned s3 = (unsigned)(__ballot((lane < 3) && sp3v) & 7ull);

    // ---- layer 4 (conv1 LIF): lane<32 = out-channel o, h = 0..2 ----
    const unsigned td  = (e_cur >> 12) & 7u;
    const unsigned td2 = (e_cur >> 15) & 7u;
    {
      double cur, t1, t2;
      t1 = (td2 & 1u) ? pre2 : pre0;  t2 = (td2 & 1u) ? pre3 : pre1;
      cur = (td & 1u) ? t2 : t1;
      if (s3 & 1u) cur += wc1b;
      cur += sp40 ? -1.0 : 0.0;
      m40 = fma(0.9, m40, cur); sp40 = m40 > 1.0;
      t1 = (td2 & 2u) ? pre2 : pre0;  t2 = (td2 & 2u) ? pre3 : pre1;
      cur = (td & 2u) ? t2 : t1;
      if (s3 & 2u) cur += wc1b;
      cur += sp41 ? -1.0 : 0.0;
      m41 = fma(0.9, m41, cur); sp41 = m41 > 1.0;
      t1 = (td2 & 4u) ? pre2 : pre0;  t2 = (td2 & 4u) ? pre3 : pre1;
      cur = (td & 4u) ? t2 : t1;
      if (s3 & 4u) cur += wc1b;
      cur += sp42 ? -1.0 : 0.0;
      m42 = fma(0.9, m42, cur); sp42 = m42 > 1.0;
    }

    // ---- rotate pipelines ----
    loA = loAn; loB = loBn; hiA = hiAn; hiB = hiBn;
    e_cur = e_nx;
    e_nx  = __builtin_amdgcn_readfirstlane(e_n2);
  }

  // ---- output: out[b,m] = bEff + sum_o spk4_final[o,m] * wEff[o] ----
  double o0 = sp40 ? wEd : 0.0;
  double o1 = sp41 ? wEd : 0.0;
  double o2 = sp42 ? wEd : 0.0;
  for (int off = 32; off > 0; off >>= 1){
    o0 += __shfl_xor(o0, off, 64);
    o1 += __shfl_xor(o1, off, 64);
    o2 += __shfl_xor(o2, off, 64);
  }
  if (lane == 0){
    const double be = *bEff;
    out[b*3+0] = (float)(o0 + be);
    out[b*3+1] = (float)(o1 + be);
    out[b*3+2] = (float)(o2 + be);
  }
}

// ---------------- host ----------------
extern "C" void kernel_launch(void* const* d_in, const int* in_sizes, int n_in,
                              void* d_out, int out_size, void* d_ws, size_t ws_size,
                              hipStream_t stream)
{
  const float* x   = (const float*)d_in[0];
  const float* u1  = (const float*)d_in[1];
  const float* u2  = (const float*)d_in[2];
  const float* u3  = (const float*)d_in[3];
  const float* W1  = (const float*)d_in[4];
  const float* b1  = (const float*)d_in[5];
  const float* W2  = (const float*)d_in[6];
  const float* b2  = (const float*)d_in[7];
  const float* W3  = (const float*)d_in[8];
  const float* b3  = (const float*)d_in[9];
  const float* Wc1 = (const float*)d_in[10];
  const float* bc1 = (const float*)d_in[11];
  const float* Wc2 = (const float*)d_in[12];
  const float* bc2 = (const float*)d_in[13];
  const float* WA  = (const float*)d_in[14];
  float* out = (float*)d_out;

  const int B = in_sizes[0] / 18;
  const int T = in_sizes[1] / (B * 12);

  char* ws = (char*)d_ws;
  float*  Wt2f  = (float*)(ws + 0);                        // 257*256*4 = 263168
  double* Stab  = (double*)(ws + 263168);                  // 2*64*256*8 = 262144
  double* wEff  = (double*)(ws + 525312);                  // 256
  double* bEff  = (double*)(ws + 525568);                  // 8
  double* probs = (double*)(ws + 525576);                  // B*24*8
  unsigned* encT= (unsigned*)(ws + 525576 + (size_t)B*24*8); // B*(T+2)*4

  hipLaunchKernelGGL(prep_weights, dim3(257), dim3(256), 0, stream,
                     W2, Wc2, bc2, WA, Wt2f, wEff, bEff);
  hipLaunchKernelGGL(prep_tab, dim3(128), dim3(256), 0, stream, W1, Stab);
  hipLaunchKernelGGL(prep_probs, dim3(B), dim3(64), 0, stream, x, probs, B);
  hipLaunchKernelGGL(prep_enc, dim3((B+255)/256, T+2), dim3(256), 0, stream,
                     u1, u2, u3, probs, encT, B, T);
  hipLaunchKernelGGL(snn_main, dim3((B+3)/4), dim3(256), 0, stream,
                     encT, b1, b2, b3, W3, Wc1, bc1, Wt2f, Stab, wEff, bEff, out, B, T);
}

// Round 15
// 683.519 us; speedup vs baseline: 2.9288x; 1.0392x over previous
//
#include <hip/hip_runtime.h>
#include <cstdint>
#include <cstddef>

typedef unsigned long long u64;

// ---------------- prep 1: W2 transpose (f32, + zero row 256) + folded output weights ----------------
__global__ void prep_weights(const float* __restrict__ W2, const float* __restrict__ Wc2,
                             const float* __restrict__ bc2, const float* __restrict__ WA,
                             float* __restrict__ Wt2f, double* __restrict__ wEff,
                             double* __restrict__ bEff)
{
  int id = blockIdx.x * 256 + (int)threadIdx.x;
  if (id < 65536){ int i = id >> 8, j = id & 255; Wt2f[(i<<8)+j] = W2[j*256+i]; }  // Wt2f[i][j] = W2[j][i]
  else if (id < 65792){ Wt2f[id] = 0.0f; }                                          // zero row (idx 256)
  if (id < 32){ double s = 0.0; for (int c=0;c<64;c++) s += (double)WA[c]*(double)Wc2[c*32+id]; wEff[id] = s; }
  if (id == 32){ double s = 0.0; for (int c=0;c<64;c++) s += (double)WA[c]*(double)bc2[c]; *bEff = s; }
}

// ---------------- prep 2: rate-encode probabilities (f64) ----------------
__global__ void prep_probs(const float* __restrict__ x, double* __restrict__ probs, int B)
{
  int b = blockIdx.x, k = (int)threadIdx.x;
  if (b >= B || k >= 24) return;
  double* pb = probs + (size_t)b*24;
  if (k >= 18){ pb[k] = -1.0; return; }
  int fk, g0, gn;
  if (k < 12){ fk = k;          g0 = 0;  gn = 12; }
  else if (k < 15){ fk = 6+(k-12);  g0 = 6;  gn = 6; }
  else           { fk = 12+(k-15); g0 = 12; gn = 6; }
  const float* xb = x + (size_t)b*18;
  double mn = (double)xb[g0], mx = mn;
  for (int f = 1; f < gn; f++){ double v = (double)xb[g0+f]; mn = fmin(mn, v); mx = fmax(mx, v); }
  double rng = mx - mn; if (rng == 0.0) rng = 1.0;
  double norm = ((double)xb[fk] - mn) / rng;
  double p = (100.0 * norm) * 0.001;
  p = fmin(fmax(p, 0.0), 1.0);
  pb[k] = p;
}

// ---------------- prep 3: pack spike bits, TRANSPOSED to (b, t), t-padded with 2 zeros ----------------
__global__ void prep_enc(const float* __restrict__ u1, const float* __restrict__ u2,
                         const float* __restrict__ u3, const double* __restrict__ probs,
                         unsigned* __restrict__ encT, int B, int T)
{
  int b = blockIdx.x * blockDim.x + (int)threadIdx.x;
  int t = blockIdx.y;
  if (b >= B) return;
  if (t >= T){ encT[(size_t)b*(T+2) + t] = 0u; return; }
  const double* pb = probs + (size_t)b*24;
  size_t r = (size_t)t * B + b;
  const float* a1 = u1 + r*12;
  const float* a2 = u2 + r*6;
  const float* a3 = u3 + r*6;
  unsigned e = 0;
  #pragma unroll
  for (int k = 0; k < 12; k++) if ((double)a1[k] < pb[k])    e |= (1u << k);
  #pragma unroll
  for (int h = 0; h < 3; h++)  if ((double)a2[h] < pb[12+h]) e |= (1u << (12+h));
  #pragma unroll
  for (int h = 0; h < 3; h++)  if ((double)a3[h] < pb[15+h]) e |= (1u << (15+h));
  encT[(size_t)b*(T+2) + t] = e;
}

// ---------------- main: one wave per batch row (R8 = best known, 685 us) ----------------
// R8 structure: enc transposed + depth-2 prefetch; W1/W3 staged in LDS; layer-2 gather
// in 4-wide windows (per-CW-mask extraction, zero-row 256 pad); loads unconditional,
// padded-slot ARITHMETIC skipped via wave-uniform branches; next-step L1 LDS gather
// overlaps window-1's L2 latency.
__global__ __launch_bounds__(256) void snn_main(
    const unsigned* __restrict__ encT,
    const float* __restrict__ b1, const float* __restrict__ b2, const float* __restrict__ b3,
    const float* __restrict__ W1, const float* __restrict__ W3,
    const float* __restrict__ Wc1, const float* __restrict__ bc1,
    const float* __restrict__ Wt2f,
    const double* __restrict__ wEff, const double* __restrict__ bEff,
    float* __restrict__ out, int B, int T)
{
  __shared__ __align__(16) float s_w1[12*256];   // s_w1[k][j] = W1[j][k]
  __shared__ __align__(16) float s_w3[257*4];    // s_w3[i][c] = W3[c][i] (c<3), col3 + row256 = 0

  const int tid  = (int)threadIdx.x;
  const int lane = tid & 63;
  const int wid  = tid >> 6;
  const int b = blockIdx.x * 4 + wid;
  const int l4 = lane << 2;
  const int lcl = (lane < 3) ? lane : 3;

  for (int i = tid; i < 3072; i += 256){ int k = i >> 8, j = i & 255; s_w1[i] = W1[j*12+k]; }
  for (int i = tid; i < 1028; i += 256){
    int r = i >> 2, c = i & 3;
    s_w3[i] = (r < 256 && c < 3) ? W3[c*256 + r] : 0.0f;
  }
  __syncthreads();
  if (b >= B) return;

  const float4 b1f = *(const float4*)(b1 + l4);
  const float4 b2f = *(const float4*)(b2 + l4);
  const double b1d0=b1f.x, b1d1=b1f.y, b1d2=b1f.z, b1d3=b1f.w;
  const double b2d0=b2f.x, b2d1=b2f.y, b2d2=b2f.z, b2d3=b2f.w;
  const double b3d = (lane < 3) ? (double)b3[lane] : 0.0;
  double wc1b=0.0, wEd=0.0, pre0=0.0, pre1=0.0, pre2=0.0, pre3=0.0;
  if (lane < 32){
    double wa = (double)Wc1[lane*3+0];
    wc1b      = (double)Wc1[lane*3+1];
    double wc = (double)Wc1[lane*3+2];
    double bd = (double)bc1[lane];
    wEd  = wEff[lane];
    pre0 = bd;            // td=0, td2=0
    pre1 = bd + wa;       // td=1, td2=0
    pre2 = bd + wc;       // td=0, td2=1
    pre3 = bd + wa + wc;  // td=1, td2=1
  }

  double m10=0,m11=0,m12=0,m13=0;
  double m20=0,m21=0,m22=0,m23=0;
  double m3v=0;
  double m40=0,m41=0,m42=0;
  bool sp20=false,sp21=false,sp22=false,sp23=false;
  bool sp3v=false;
  bool sp40=false,sp41=false,sp42=false;

  const unsigned* encTb = encT + (size_t)b * (T + 2);

  unsigned e_cur = __builtin_amdgcn_readfirstlane(encTb[0]);
  unsigned e_nx  = __builtin_amdgcn_readfirstlane(encTb[1]);
  double ca0=b1d0, ca1=b1d1, ca2=b1d2, ca3=b1d3;
  {
    unsigned w = e_cur & 0xFFFu;
    while (w){
      int k = __builtin_ctz(w); w &= w-1;
      const float4 r = *(const float4*)&s_w1[(k<<8) + l4];
      ca0 += (double)r.x; ca1 += (double)r.y; ca2 += (double)r.z; ca3 += (double)r.w;
    }
  }

  for (int t = 0; t < T; t++){
    // ---- layer 1 membrane update (current pre-accumulated in ca*) ----
    m10 = fma(0.9, m10, ca0);
    m11 = fma(0.9, m11, ca1);
    m12 = fma(0.9, m12, ca2);
    m13 = fma(0.9, m13, ca3);
    const bool sp10 = m10 > 1.0; u64 w0 = __ballot(sp10);
    const bool sp11 = m11 > 1.0; u64 w1 = __ballot(sp11);
    const bool sp12 = m12 > 1.0; u64 w2 = __ballot(sp12);
    const bool sp13 = m13 > 1.0; u64 w3m = __ballot(sp13);

    // ---- layer 2, first window: one row per CW-mask (zero-row 256 when empty) ----
    int i0 = w0  ? (((int)__builtin_ctzll(w0) <<2)|0) : 256;  w0  &= w0 -1;
    int i1 = w1  ? (((int)__builtin_ctzll(w1) <<2)|1) : 256;  w1  &= w1 -1;
    int i2 = w2  ? (((int)__builtin_ctzll(w2) <<2)|2) : 256;  w2  &= w2 -1;
    int i3 = w3m ? (((int)__builtin_ctzll(w3m)<<2)|3) : 256;  w3m &= w3m-1;
    const float4 g0 = *(const float4*)(Wt2f + ((size_t)i0<<8) + l4);
    const float4 g1 = *(const float4*)(Wt2f + ((size_t)i1<<8) + l4);
    const float4 g2 = *(const float4*)(Wt2f + ((size_t)i2<<8) + l4);
    const float4 g3 = *(const float4*)(Wt2f + ((size_t)i3<<8) + l4);

    // prefetch enc for t+2 (sequential 4B, L1-hot; padded rows give 0 past T-1)
    const unsigned e_n2 = encTb[t+2];

    // ---- overlap first-window latency: next-step layer-1 gather from LDS ----
    ca0 = (sp10 ? -1.0 : 0.0) + b1d0;
    ca1 = (sp11 ? -1.0 : 0.0) + b1d1;
    ca2 = (sp12 ? -1.0 : 0.0) + b1d2;
    ca3 = (sp13 ? -1.0 : 0.0) + b1d3;
    {
      unsigned w = e_nx & 0xFFFu;
      while (w){
        int k = __builtin_ctz(w); w &= w-1;
        const float4 r = *(const float4*)&s_w1[(k<<8) + l4];
        ca0 += (double)r.x; ca1 += (double)r.y; ca2 += (double)r.z; ca3 += (double)r.w;
      }
    }

    // ---- consume first window: skip padded slots (wave-uniform branches) ----
    double c0 = (sp20 ? -1.0 : 0.0) + b2d0;
    double c1 = (sp21 ? -1.0 : 0.0) + b2d1;
    double c2 = (sp22 ? -1.0 : 0.0) + b2d2;
    double c3 = (sp23 ? -1.0 : 0.0) + b2d3;
    if (i0 != 256){ c0 += (double)g0.x; c1 += (double)g0.y; c2 += (double)g0.z; c3 += (double)g0.w; }
    if (i1 != 256){ c0 += (double)g1.x; c1 += (double)g1.y; c2 += (double)g1.z; c3 += (double)g1.w; }
    if (i2 != 256){ c0 += (double)g2.x; c1 += (double)g2.y; c2 += (double)g2.z; c3 += (double)g2.w; }
    if (i3 != 256){ c0 += (double)g3.x; c1 += (double)g3.y; c2 += (double)g3.z; c3 += (double)g3.w; }

    // ---- remaining windows: loads unconditional, consumes guarded ----
    while (w0 | w1 | w2 | w3m){
      int j0 = w0  ? (((int)__builtin_ctzll(w0) <<2)|0) : 256;  w0  &= w0 -1;
      int j1 = w1  ? (((int)__builtin_ctzll(w1) <<2)|1) : 256;  w1  &= w1 -1;
      int j2 = w2  ? (((int)__builtin_ctzll(w2) <<2)|2) : 256;  w2  &= w2 -1;
      int j3 = w3m ? (((int)__builtin_ctzll(w3m)<<2)|3) : 256;  w3m &= w3m-1;
      const float4 h0 = *(const float4*)(Wt2f + ((size_t)j0<<8) + l4);
      const float4 h1 = *(const float4*)(Wt2f + ((size_t)j1<<8) + l4);
      const float4 h2 = *(const float4*)(Wt2f + ((size_t)j2<<8) + l4);
      const float4 h3 = *(const float4*)(Wt2f + ((size_t)j3<<8) + l4);
      if (j0 != 256){ c0 += (double)h0.x; c1 += (double)h0.y; c2 += (double)h0.z; c3 += (double)h0.w; }
      if (j1 != 256){ c0 += (double)h1.x; c1 += (double)h1.y; c2 += (double)h1.z; c3 += (double)h1.w; }
      if (j2 != 256){ c0 += (double)h2.x; c1 += (double)h2.y; c2 += (double)h2.z; c3 += (double)h2.w; }
      if (j3 != 256){ c0 += (double)h3.x; c1 += (double)h3.y; c2 += (double)h3.z; c3 += (double)h3.w; }
    }

    m20 = fma(0.9, m20, c0);
    m21 = fma(0.9, m21, c1);
    m22 = fma(0.9, m22, c2);
    m23 = fma(0.9, m23, c3);
    sp20 = m20 > 1.0; u64 v0 = __ballot(sp20);
    sp21 = m21 > 1.0; u64 v1 = __ballot(sp21);
    sp22 = m22 > 1.0; u64 v2 = __ballot(sp22);
    sp23 = m23 > 1.0; u64 v3 = __ballot(sp23);

    // ---- layer 3 from LDS: consumes guarded per slot ----
    double cl3 = (sp3v ? -1.0 : 0.0) + b3d;
    while (v0 | v1 | v2 | v3){
      int j0 = v0 ? (((int)__builtin_ctzll(v0)<<2)|0) : 256;  v0 &= v0-1;
      int j1 = v1 ? (((int)__builtin_ctzll(v1)<<2)|1) : 256;  v1 &= v1-1;
      int j2 = v2 ? (((int)__builtin_ctzll(v2)<<2)|2) : 256;  v2 &= v2-1;
      int j3 = v3 ? (((int)__builtin_ctzll(v3)<<2)|3) : 256;  v3 &= v3-1;
      if (j0 != 256) cl3 += (double)s_w3[(j0<<2) + lcl];
      if (j1 != 256) cl3 += (double)s_w3[(j1<<2) + lcl];
      if (j2 != 256) cl3 += (double)s_w3[(j2<<2) + lcl];
      if (j3 != 256) cl3 += (double)s_w3[(j3<<2) + lcl];
    }
    m3v = fma(0.9, m3v, cl3);
    sp3v = m3v > 1.0;
    const unsigned s3 = (unsigned)(__ballot((lane < 3) && sp3v) & 7ull);

    // ---- layer 4 (conv1 LIF): lane<32 = out-channel o, h = 0..2 ----
    const unsigned td  = (e_cur >> 12) & 7u;
    const unsigned td2 = (e_cur >> 15) & 7u;
    {
      double cur, t1, t2;
      t1 = (td2 & 1u) ? pre2 : pre0;  t2 = (td2 & 1u) ? pre3 : pre1;
      cur = (td & 1u) ? t2 : t1;
      if (s3 & 1u) cur += wc1b;
      cur += sp40 ? -1.0 : 0.0;
      m40 = fma(0.9, m40, cur); sp40 = m40 > 1.0;
      t1 = (td2 & 2u) ? pre2 : pre0;  t2 = (td2 & 2u) ? pre3 : pre1;
      cur = (td & 2u) ? t2 : t1;
      if (s3 & 2u) cur += wc1b;
      cur += sp41 ? -1.0 : 0.0;
      m41 = fma(0.9, m41, cur); sp41 = m41 > 1.0;
      t1 = (td2 & 4u) ? pre2 : pre0;  t2 = (td2 & 4u) ? pre3 : pre1;
      cur = (td & 4u) ? t2 : t1;
      if (s3 & 4u) cur += wc1b;
      cur += sp42 ? -1.0 : 0.0;
      m42 = fma(0.9, m42, cur); sp42 = m42 > 1.0;
    }

    // ---- rotate enc pipeline ----
    e_cur = e_nx;
    e_nx  = __builtin_amdgcn_readfirstlane(e_n2);
  }

  // ---- output: out[b,m] = bEff + sum_o spk4_final[o,m] * wEff[o] ----
  double o0 = sp40 ? wEd : 0.0;
  double o1 = sp41 ? wEd : 0.0;
  double o2 = sp42 ? wEd : 0.0;
  for (int off = 32; off > 0; off >>= 1){
    o0 += __shfl_xor(o0, off, 64);
    o1 += __shfl_xor(o1, off, 64);
    o2 += __shfl_xor(o2, off, 64);
  }
  if (lane == 0){
    const double be = *bEff;
    out[b*3+0] = (float)(o0 + be);
    out[b*3+1] = (float)(o1 + be);
    out[b*3+2] = (float)(o2 + be);
  }
}

// ---------------- host ----------------
extern "C" void kernel_launch(void* const* d_in, const int* in_sizes, int n_in,
                              void* d_out, int out_size, void* d_ws, size_t ws_size,
                              hipStream_t stream)
{
  const float* x   = (const float*)d_in[0];
  const float* u1  = (const float*)d_in[1];
  const float* u2  = (const float*)d_in[2];
  const float* u3  = (const float*)d_in[3];
  const float* W1  = (const float*)d_in[4];
  const float* b1  = (const float*)d_in[5];
  const float* W2  = (const float*)d_in[6];
  const float* b2  = (const float*)d_in[7];
  const float* W3  = (const float*)d_in[8];
  const float* b3  = (const float*)d_in[9];
  const float* Wc1 = (const float*)d_in[10];
  const float* bc1 = (const float*)d_in[11];
  const float* Wc2 = (const float*)d_in[12];
  const float* bc2 = (const float*)d_in[13];
  const float* WA  = (const float*)d_in[14];
  float* out = (float*)d_out;

  const int B = in_sizes[0] / 18;
  const int T = in_sizes[1] / (B * 12);

  char* ws = (char*)d_ws;
  float*  Wt2f  = (float*)(ws + 0);                        // 257*256*4 = 263168
  double* wEff  = (double*)(ws + 263168);                  // 256
  double* bEff  = (double*)(ws + 263424);                  // 8
  double* probs = (double*)(ws + 263432);                  // B*24*8
  unsigned* encT= (unsigned*)(ws + 263432 + (size_t)B*24*8); // B*(T+2)*4

  hipLaunchKernelGGL(prep_weights, dim3(257), dim3(256), 0, stream,
                     W2, Wc2, bc2, WA, Wt2f, wEff, bEff);
  hipLaunchKernelGGL(prep_probs, dim3(B), dim3(64), 0, stream, x, probs, B);
  hipLaunchKernelGGL(prep_enc, dim3((B+255)/256, T+2), dim3(256), 0, stream,
                     u1, u2, u3, probs, encT, B, T);
  hipLaunchKernelGGL(snn_main, dim3((B+3)/4), dim3(256), 0, stream,
                     encT, b1, b2, b3, W1, W3, Wc1, bc1, Wt2f, wEff, bEff, out, B, T);
}